// Round 3
// 542.992 us; speedup vs baseline: 1.0429x; 1.0429x over previous
//
#include <hip/hip_runtime.h>

#define UNITS 512
#define EMBD  256
#define BATCH 64
#define TLEN  2048

typedef __bf16 bf16x8 __attribute__((ext_vector_type(8)));
typedef float  f32x4  __attribute__((ext_vector_type(4)));

__device__ __forceinline__ unsigned short f2bf(float x) {
  return __builtin_bit_cast(unsigned short, (__bf16)x);
}
__device__ __forceinline__ float fast_tanh(float x) {
  float e = __expf(2.0f * x);
  return __fdividef(e - 1.0f, e + 1.0f);
}
__device__ __forceinline__ float fast_sigmoid(float x) {
  return __fdividef(1.0f, 1.0f + __expf(-x));
}

// ---------------------------------------------------------------------------
// Shared split-K small-GEMM core (after Asm staged in LDS):
//   out[m][bx*64 + cl] = dot(Asm[:K], Bm[:, c]) (+b1)(+b2)
// block = 256 = 64 cols x 4 k-segments.
// ---------------------------------------------------------------------------
__device__ __forceinline__ void dot_core(const float* Asm, float (*red)[64],
                                         const float* __restrict__ Bm, int ldb,
                                         const float* __restrict__ b1,
                                         const float* __restrict__ b2,
                                         float* __restrict__ out, int ldo,
                                         int K, int bx, int m) {
  const int cl = threadIdx.x & 63;
  const int ks = threadIdx.x >> 6;            // 0..3
  const int c  = (bx << 6) + cl;
  const int kl = K >> 2;
  const float* bp = Bm + (size_t)(ks * kl) * ldb + c;
  float acc = 0.0f;
#pragma unroll 8
  for (int kk = 0; kk < kl; ++kk)
    acc = fmaf(Asm[ks * kl + kk], bp[(size_t)kk * ldb], acc);
  red[ks][cl] = acc;
  __syncthreads();
  if (threadIdx.x < 64) {
    int cc = (bx << 6) + threadIdx.x;
    float v = red[0][threadIdx.x] + red[1][threadIdx.x] +
              red[2][threadIdx.x] + red[3][threadIdx.x];
    if (b1) v += b1[cc];
    if (b2) v += b2[cc];
    out[(size_t)m * ldo + cc] = v;
  }
}

// ---------------------------------------------------------------------------
// Launch 1 (fused, all independent): prep (Wa->frag-order bf16, zero gO/gL),
// x = inputs@Wi + bi, u = h@Ua + ba_u + ba_w, rec_zr = h@RK[:, :1024].
// grid = 1024 (prep) + 512 (x) + 512 (u) + 1024 (rec_zr) = 3072 blocks.
// ---------------------------------------------------------------------------
__global__ void stage1_kernel(const float* __restrict__ Wa,
                              unsigned short* __restrict__ WaF,
                              float* __restrict__ gO, float* __restrict__ gL,
                              const float* __restrict__ inputs,
                              const float* __restrict__ Wi,
                              const float* __restrict__ bi,
                              float* __restrict__ xbuf,
                              const float* __restrict__ h_tm1,
                              const float* __restrict__ Ua,
                              const float* __restrict__ ba_u,
                              const float* __restrict__ ba_w,
                              float* __restrict__ ubuf,
                              const float* __restrict__ rk,
                              float* __restrict__ rec_zr) {
  __shared__ float Asm[512];
  __shared__ float red[4][64];
  int bid = blockIdx.x;
  if (bid < 1024) {                       // ---- prep ----
    int idx = bid * 256 + threadIdx.x;    // 0..262143
    int j  = idx & 7;
    int l  = (idx >> 3) & 63;
    int nt = (idx >> 9) & 31;
    int ks = idx >> 14;
    int k = ks * 32 + ((l >> 4) << 3) + j;
    int n = (nt << 4) + (l & 15);
    WaF[idx] = f2bf(Wa[k * 512 + n]);
    if (idx < BATCH * UNITS) gO[idx] = 0.0f;
    if (idx < BATCH)         gL[idx] = 0.0f;
    return;
  }
  bid -= 1024;
  if (bid < 512) {                        // ---- x = inputs@Wi + bi ----
    int bx = bid & 7, m = bid >> 3;
    for (int k = threadIdx.x; k < 256; k += 256) Asm[k] = inputs[m * 256 + k];
    __syncthreads();
    dot_core(Asm, red, Wi, 512, bi, nullptr, xbuf, 512, 256, bx, m);
    return;
  }
  bid -= 512;
  if (bid < 512) {                        // ---- u = h@Ua + ba_u + ba_w ----
    int bx = bid & 7, m = bid >> 3;
    for (int k = threadIdx.x; k < 512; k += 256) Asm[k] = h_tm1[m * 512 + k];
    __syncthreads();
    dot_core(Asm, red, Ua, 512, ba_u, ba_w, ubuf, 512, 512, bx, m);
    return;
  }
  bid -= 512;
  {                                       // ---- rec_zr = h@RK[:, :1024] ----
    int bx = bid & 15, m = bid >> 4;
    for (int k = threadIdx.x; k < 512; k += 256) Asm[k] = h_tm1[m * 512 + k];
    __syncthreads();
    dot_core(Asm, red, rk, 1536, nullptr, nullptr, rec_zr, 1024, 512, bx, m);
  }
}

// ---------------------------------------------------------------------------
// xg = x @ kernel + bias.  grid = (24, 64).
// ---------------------------------------------------------------------------
__global__ void xg_kernel(const float* __restrict__ xbuf,
                          const float* __restrict__ kern,
                          const float* __restrict__ bias,
                          float* __restrict__ xg) {
  __shared__ float Asm[512];
  __shared__ float red[4][64];
  int m = blockIdx.y;
  for (int k = threadIdx.x; k < 512; k += 256) Asm[k] = xbuf[m * 512 + k];
  __syncthreads();
  dot_core(Asm, red, kern, 1536, bias, nullptr, xg, 1536, 512, blockIdx.x, m);
}

// ---------------------------------------------------------------------------
// K3: fused attention-score + softmax partials + weighted context sum.
// Block = (batch b, 64 t-rows). N=512 in regs (acc[4][8] f32x4 = 128 AGPR).
// Pipeline: A (ctx) prefetched 2 k-steps ahead in regs -> bf16 -> LDS dbuf;
// B (WaF) loaded L2->reg in frag order, 1 step ahead; one barrier per step.
// (Exact round-0-measured structure: plain __syncthreads, no raw barriers.)
// ---------------------------------------------------------------------------
__launch_bounds__(256, 2)
__global__ void score_ctx_kernel(const float* __restrict__ ctx,
                                 const unsigned short* __restrict__ WaF,
                                 const float* __restrict__ uvec,
                                 const float* __restrict__ Va,
                                 float* __restrict__ gO,
                                 float* __restrict__ gL) {
  __shared__ unsigned short As[2][64][40];   // 2 x (64 rows x 32k + 8 pad) bf16
  __shared__ float sS[64];
  __shared__ float sE[64];

  const int b   = blockIdx.y;
  const int tc  = blockIdx.x;
  const int tid = threadIdx.x;
  const int lane  = tid & 63;
  const int w     = tid >> 6;      // wave 0..3
  const int row_a = lane & 15;
  const int kq    = lane >> 4;

  const float* ctile = ctx + ((size_t)b * TLEN + (size_t)tc * 64) * UNITS;

  if (tid < 64) sS[tid] = 0.0f;

  f32x4 acc[4][8];
#pragma unroll
  for (int mt = 0; mt < 4; ++mt)
#pragma unroll
    for (int nt = 0; nt < 8; ++nt)
      acc[mt][nt] = (f32x4){0.0f, 0.0f, 0.0f, 0.0f};

  const int r_st = tid & 63;       // A staging row
  const int half = tid >> 6;       // which 8-float slice of the 32-k row

  const float4* abase = (const float4*)(ctile + r_st * UNITS + half * 8);
  // step ks slice for this thread: abase[ks*8], abase[ks*8+1]
  const bf16x8* bbase = (const bf16x8*)WaF + lane;

  float4 pa0[2], pa1[2];
  pa0[0] = abase[0]; pa0[1] = abase[1];        // A(0)
  pa1[0] = abase[8]; pa1[1] = abase[9];        // A(1)

  bf16x8 bcur[8], bnxt[8];
#pragma unroll
  for (int nt = 0; nt < 8; ++nt)
    bcur[nt] = bbase[(size_t)((w << 3) + nt) * 64];   // B(0)

  // stage A(0) into LDS buf 0
  {
    ushort4 q0 = make_ushort4(f2bf(pa0[0].x), f2bf(pa0[0].y), f2bf(pa0[0].z), f2bf(pa0[0].w));
    ushort4 q1 = make_ushort4(f2bf(pa0[1].x), f2bf(pa0[1].y), f2bf(pa0[1].z), f2bf(pa0[1].w));
    *(ushort4*)&As[0][r_st][half * 8]     = q0;
    *(ushort4*)&As[0][r_st][half * 8 + 4] = q1;
  }

#pragma unroll
  for (int ks = 0; ks < 16; ++ks) {
    const int cur = ks & 1;
    __syncthreads();                       // As[cur] visible; prev reads done
    // A fragments from LDS
    bf16x8 af[4];
#pragma unroll
    for (int mt = 0; mt < 4; ++mt)
      af[mt] = *(const bf16x8*)&As[cur][mt * 16 + row_a][kq * 8];
    // prefetch A(ks+2) into the now-free slot
    if (ks < 14) {
      float4* pdst = (cur == 0) ? pa0 : pa1;
      pdst[0] = abase[(ks + 2) * 8];
      pdst[1] = abase[(ks + 2) * 8 + 1];
    }
    // prefetch B(ks+1) straight from L2
    if (ks < 15) {
#pragma unroll
      for (int nt = 0; nt < 8; ++nt)
        bnxt[nt] = bbase[(size_t)((ks + 1) * 32 + (w << 3) + nt) * 64];
    }
    // MFMA: 4 m-tiles x 8 n-tiles
#pragma unroll
    for (int nt = 0; nt < 8; ++nt)
#pragma unroll
      for (int mt = 0; mt < 4; ++mt)
        acc[mt][nt] = __builtin_amdgcn_mfma_f32_16x16x32_bf16(af[mt], bcur[nt], acc[mt][nt], 0, 0, 0);
    // stage A(ks+1) (loaded 2 steps ago) into the other LDS buffer
    if (ks < 15) {
      const float4* psrc = (cur == 0) ? pa1 : pa0;
      ushort4 q0 = make_ushort4(f2bf(psrc[0].x), f2bf(psrc[0].y), f2bf(psrc[0].z), f2bf(psrc[0].w));
      ushort4 q1 = make_ushort4(f2bf(psrc[1].x), f2bf(psrc[1].y), f2bf(psrc[1].z), f2bf(psrc[1].w));
      *(ushort4*)&As[1 - cur][r_st][half * 8]     = q0;
      *(ushort4*)&As[1 - cur][r_st][half * 8 + 4] = q1;
#pragma unroll
      for (int nt = 0; nt < 8; ++nt) bcur[nt] = bnxt[nt];
    }
  }

  // ---- epilogue: s_t = sum_n tanh(y + u) * Va ----
  float uvals[8], vvals[8];
#pragma unroll
  for (int nt = 0; nt < 8; ++nt) {
    int n_g = (w << 7) + (nt << 4) + row_a;
    uvals[nt] = uvec[b * UNITS + n_g];
    vvals[nt] = Va[n_g];
  }
#pragma unroll
  for (int mt = 0; mt < 4; ++mt) {
#pragma unroll
    for (int r = 0; r < 4; ++r) {
      float v = 0.0f;
#pragma unroll
      for (int nt = 0; nt < 8; ++nt)
        v += fast_tanh(acc[mt][nt][r] + uvals[nt]) * vvals[nt];
      v += __shfl_xor(v, 1);
      v += __shfl_xor(v, 2);
      v += __shfl_xor(v, 4);
      v += __shfl_xor(v, 8);
      if (row_a == 0) atomicAdd(&sS[mt * 16 + kq * 4 + r], v);
    }
  }
  __syncthreads();
  if (tid < 64) sE[tid] = __expf(sS[tid]);
  __syncthreads();
  if (tid < 64) {
    float e = sE[tid];
#pragma unroll
    for (int off = 1; off < 64; off <<= 1) e += __shfl_xor(e, off);
    if (tid == 0) atomicAdd(&gL[b], e);
  }
  // ---- weighted context accumulation (tile L2-hot; coalesced re-read) ----
#pragma unroll
  for (int cc = 0; cc < 2; ++cc) {
    int c = cc * 256 + tid;
    float o = 0.0f;
#pragma unroll 8
    for (int t = 0; t < 64; ++t)
      o = fmaf(sE[t], ctile[t * UNITS + c], o);
    atomicAdd(&gO[b * UNITS + c], o);
  }
}

// ---------------------------------------------------------------------------
// cg = (gO/gL) @ attention_kernel.  grid = (24, 64).
// ---------------------------------------------------------------------------
__global__ void cg_kernel(const float* __restrict__ gO,
                          const float* __restrict__ gL,
                          const float* __restrict__ ak,
                          float* __restrict__ cg) {
  __shared__ float Asm[512];
  __shared__ float red[4][64];
  int m = blockIdx.y;
  float sc = __fdividef(1.0f, gL[m]);
  for (int k = threadIdx.x; k < 512; k += 256) Asm[k] = gO[m * 512 + k] * sc;
  __syncthreads();
  dot_core(Asm, red, ak, 1536, nullptr, nullptr, cg, 1536, 512, blockIdx.x, m);
}

// ---------------------------------------------------------------------------
// rec_h = (r * h_tm1) @ RK[:, 1024:], with r-gate computed inline during
// staging (replaces the former gates_kernel).  grid = (8, 64).
// ---------------------------------------------------------------------------
__global__ void rech_kernel(const float* __restrict__ xg,
                            const float* __restrict__ reczr,
                            const float* __restrict__ cg,
                            const float* __restrict__ h,
                            const float* __restrict__ rkh,   // rk + 1024
                            float* __restrict__ out) {
  __shared__ float Asm[512];
  __shared__ float red[4][64];
  int m = blockIdx.y;
  for (int k = threadIdx.x; k < 512; k += 256) {
    float r = fast_sigmoid(xg[m * 1536 + 512 + k] + reczr[m * 1024 + 512 + k] +
                           cg[m * 1536 + 512 + k]);
    Asm[k] = r * h[m * 512 + k];
  }
  __syncthreads();
  dot_core(Asm, red, rkh, 1536, nullptr, nullptr, out, 512, 512, blockIdx.x, m);
}

// ---------------------------------------------------------------------------
// out = h_new @ Wo + bo, with h_new computed inline during staging
// (replaces the former newh_kernel); block x==0 also stores h_new.
// grid = (8, 64).
// ---------------------------------------------------------------------------
__global__ void out_kernel(const float* __restrict__ xg,
                           const float* __restrict__ reczr,
                           const float* __restrict__ cg,
                           const float* __restrict__ rech,
                           const float* __restrict__ h_tm1,
                           const float* __restrict__ Wo,
                           const float* __restrict__ bo,
                           float* __restrict__ out,
                           float* __restrict__ hout) {
  __shared__ float Asm[512];
  __shared__ float red[4][64];
  int m = blockIdx.y;
  for (int k = threadIdx.x; k < 512; k += 256) {
    float z  = fast_sigmoid(xg[m * 1536 + k] + reczr[m * 1024 + k] + cg[m * 1536 + k]);
    float hb = fast_tanh(xg[m * 1536 + 1024 + k] + rech[m * 512 + k] +
                         cg[m * 1536 + 1024 + k]);
    float hn = z * h_tm1[m * 512 + k] + (1.0f - z) * hb;
    Asm[k] = hn;
    if (blockIdx.x == 0) hout[m * 512 + k] = hn;
  }
  __syncthreads();
  dot_core(Asm, red, Wo, 512, bo, nullptr, out, 512, 512, blockIdx.x, m);
}

// ---------------------------------------------------------------------------
extern "C" void kernel_launch(void* const* d_in, const int* in_sizes, int n_in,
                              void* d_out, int out_size, void* d_ws, size_t ws_size,
                              hipStream_t stream) {
  (void)in_sizes; (void)n_in; (void)out_size; (void)ws_size;
  const float* inputs = (const float*)d_in[0];
  const float* h_tm1  = (const float*)d_in[1];
  const float* ctx    = (const float*)d_in[2];
  const float* Wi     = (const float*)d_in[3];
  const float* bi     = (const float*)d_in[4];
  const float* kern   = (const float*)d_in[5];
  const float* rk     = (const float*)d_in[6];
  const float* ak     = (const float*)d_in[7];
  const float* bias   = (const float*)d_in[8];
  const float* Wa     = (const float*)d_in[9];
  const float* ba_w   = (const float*)d_in[10];
  const float* Ua     = (const float*)d_in[11];
  const float* ba_u   = (const float*)d_in[12];
  const float* Va     = (const float*)d_in[13];
  // d_in[14] = ba_v: unused (softmax is shift-invariant)
  const float* Wo     = (const float*)d_in[15];
  const float* bo     = (const float*)d_in[16];

  float* out = (float*)d_out;               // [64][512] out, then [64][512] h
  float* ws  = (float*)d_ws;
  unsigned short* WaF = (unsigned short*)ws;    // 262144 bf16
  float* gO     = ws + 131072;   // [64][512]
  float* gL     = ws + 163840;   // [64]
  float* xbuf   = ws + 163904;   // [64][512]
  float* xg     = ws + 196672;   // [64][1536]
  float* ubuf   = ws + 294976;   // [64][512]
  float* rec_zr = ws + 327744;   // [64][1024]
  float* cg     = ws + 393280;   // [64][1536]
  float* rech   = ws + 491584;   // [64][512]

  // L1: prep + x + u + rec_zr (all independent)
  stage1_kernel<<<3072, 256, 0, stream>>>(Wa, WaF, gO, gL,
                                          inputs, Wi, bi, xbuf,
                                          h_tm1, Ua, ba_u, ba_w, ubuf,
                                          rk, rec_zr);
  // L2: xg = x @ kernel + bias
  xg_kernel<<<dim3(24, 64), 256, 0, stream>>>(xbuf, kern, bias, xg);
  // L3: fused attention
  score_ctx_kernel<<<dim3(32, 64), 256, 0, stream>>>(ctx, WaF, ubuf, Va, gO, gL);
  // L4: cg = (gO/gL) @ attention_kernel
  cg_kernel<<<dim3(24, 64), 256, 0, stream>>>(gO, gL, ak, cg);
  // L5: rec_h = (r*h) @ RK[:, 1024:]  (r computed inline)
  rech_kernel<<<dim3(8, 64), 256, 0, stream>>>(xg, rec_zr, cg, h_tm1, rk + 1024, rech);
  // L6: h_new inline; out = h_new @ Wo + bo; h_new also stored
  out_kernel<<<dim3(8, 64), 256, 0, stream>>>(xg, rec_zr, cg, rech, h_tm1, Wo, bo,
                                              out, out + BATCH * UNITS);
}

// Round 4
// 533.869 us; speedup vs baseline: 1.0607x; 1.0171x over previous
//
#include <hip/hip_runtime.h>

#define UNITS 512
#define EMBD  256
#define BATCH 64
#define TLEN  2048

typedef __bf16 bf16x8 __attribute__((ext_vector_type(8)));
typedef float  f32x4  __attribute__((ext_vector_type(4)));

__device__ __forceinline__ unsigned short f2bf(float x) {
  return __builtin_bit_cast(unsigned short, (__bf16)x);
}
__device__ __forceinline__ float fast_tanh(float x) {
  float e = __expf(2.0f * x);
  return __fdividef(e - 1.0f, e + 1.0f);
}
__device__ __forceinline__ float fast_sigmoid(float x) {
  return __fdividef(1.0f, 1.0f + __expf(-x));
}

// ---------------------------------------------------------------------------
// Shared split-K small-GEMM core (after Asm staged in LDS):
//   out[m][bx*64 + cl] = dot(Asm[:K], Bm[:, c]) (+b1)(+b2)
// block = 256 = 64 cols x 4 k-segments.
// ---------------------------------------------------------------------------
__device__ __forceinline__ void dot_core(const float* Asm, float (*red)[64],
                                         const float* __restrict__ Bm, int ldb,
                                         const float* __restrict__ b1,
                                         const float* __restrict__ b2,
                                         float* __restrict__ out, int ldo,
                                         int K, int bx, int m) {
  const int cl = threadIdx.x & 63;
  const int ks = threadIdx.x >> 6;            // 0..3
  const int c  = (bx << 6) + cl;
  const int kl = K >> 2;
  const float* bp = Bm + (size_t)(ks * kl) * ldb + c;
  float acc = 0.0f;
#pragma unroll 8
  for (int kk = 0; kk < kl; ++kk)
    acc = fmaf(Asm[ks * kl + kk], bp[(size_t)kk * ldb], acc);
  red[ks][cl] = acc;
  __syncthreads();
  if (threadIdx.x < 64) {
    int cc = (bx << 6) + threadIdx.x;
    float v = red[0][threadIdx.x] + red[1][threadIdx.x] +
              red[2][threadIdx.x] + red[3][threadIdx.x];
    if (b1) v += b1[cc];
    if (b2) v += b2[cc];
    out[(size_t)m * ldo + cc] = v;
  }
}

// ---------------------------------------------------------------------------
// Launch 1 (fused, all independent): prep (Wa->frag-order bf16, zero gO/gL),
// x = inputs@Wi + bi, u = h@Ua + ba_u + ba_w, rec_zr = h@RK[:, :1024].
// prep: coalesced READS of Wa (scattered 2B writes to L2 don't stall).
// ---------------------------------------------------------------------------
__global__ void stage1_kernel(const float* __restrict__ Wa,
                              unsigned short* __restrict__ WaF,
                              float* __restrict__ gO, float* __restrict__ gL,
                              const float* __restrict__ inputs,
                              const float* __restrict__ Wi,
                              const float* __restrict__ bi,
                              float* __restrict__ xbuf,
                              const float* __restrict__ h_tm1,
                              const float* __restrict__ Ua,
                              const float* __restrict__ ba_u,
                              const float* __restrict__ ba_w,
                              float* __restrict__ ubuf,
                              const float* __restrict__ rk,
                              float* __restrict__ rec_zr) {
  __shared__ float Asm[512];
  __shared__ float red[4][64];
  int bid = blockIdx.x;
  if (bid < 1024) {                       // ---- prep ----
    int flat = bid * 256 + threadIdx.x;   // = k*512 + n  (coalesced read)
    int k = flat >> 9;
    int n = flat & 511;
    int ks = k >> 5;
    int hi = (k >> 3) & 3;
    int j  = k & 7;
    int l  = (hi << 4) | (n & 15);
    int nt = n >> 4;
    int idx = (ks << 14) | (nt << 9) | (l << 3) | j;
    WaF[idx] = f2bf(Wa[flat]);
    if (flat < BATCH * UNITS) gO[flat] = 0.0f;
    if (flat < BATCH)         gL[flat] = 0.0f;
    return;
  }
  bid -= 1024;
  if (bid < 512) {                        // ---- x = inputs@Wi + bi ----
    int bx = bid & 7, m = bid >> 3;
    for (int k = threadIdx.x; k < 256; k += 256) Asm[k] = inputs[m * 256 + k];
    __syncthreads();
    dot_core(Asm, red, Wi, 512, bi, nullptr, xbuf, 512, 256, bx, m);
    return;
  }
  bid -= 512;
  if (bid < 512) {                        // ---- u = h@Ua + ba_u + ba_w ----
    int bx = bid & 7, m = bid >> 3;
    for (int k = threadIdx.x; k < 512; k += 256) Asm[k] = h_tm1[m * 512 + k];
    __syncthreads();
    dot_core(Asm, red, Ua, 512, ba_u, ba_w, ubuf, 512, 512, bx, m);
    return;
  }
  bid -= 512;
  {                                       // ---- rec_zr = h@RK[:, :1024] ----
    int bx = bid & 15, m = bid >> 4;
    for (int k = threadIdx.x; k < 512; k += 256) Asm[k] = h_tm1[m * 512 + k];
    __syncthreads();
    dot_core(Asm, red, rk, 1536, nullptr, nullptr, rec_zr, 1024, 512, bx, m);
  }
}

// ---------------------------------------------------------------------------
// xg = x @ kernel + bias.  grid = (24, 64).
// ---------------------------------------------------------------------------
__global__ void xg_kernel(const float* __restrict__ xbuf,
                          const float* __restrict__ kern,
                          const float* __restrict__ bias,
                          float* __restrict__ xg) {
  __shared__ float Asm[512];
  __shared__ float red[4][64];
  int m = blockIdx.y;
  for (int k = threadIdx.x; k < 512; k += 256) Asm[k] = xbuf[m * 512 + k];
  __syncthreads();
  dot_core(Asm, red, kern, 1536, bias, nullptr, xg, 1536, 512, blockIdx.x, m);
}

// ---------------------------------------------------------------------------
// K3: fused attention-score + softmax partials + weighted context sum.
// v3: FULL-TILE LDS, ONE barrier. Stage ctx tile (64x512 f32 -> bf16,
// 66.5 KB LDS) with perfectly-coalesced flat float4 loads, single
// __syncthreads, then a barrier-free 16-step MFMA loop (ds_read_b128 A +
// L2-hot B loads + 32 MFMA/step) with no vmcnt(0) drains anywhere.
// 2 blocks/CU double-buffer each other (one stages while one computes).
// LDS row pad +8 bf16 => uniform minimal bank spread for both ds_write_b64
// (stage) and ds_read_b128 (frags).
// ---------------------------------------------------------------------------
__launch_bounds__(256, 2)
__global__ void score_ctx_kernel(const float* __restrict__ ctx,
                                 const unsigned short* __restrict__ WaF,
                                 const float* __restrict__ uvec,
                                 const float* __restrict__ Va,
                                 float* __restrict__ gO,
                                 float* __restrict__ gL) {
  __shared__ unsigned short As[64][520];     // 64 rows x 512 bf16 + 8 pad
  __shared__ float sS[64];
  __shared__ float sE[64];

  const int b   = blockIdx.y;
  const int tc  = blockIdx.x;
  const int tid = threadIdx.x;
  const int lane  = tid & 63;
  const int w     = tid >> 6;      // wave 0..3
  const int row_a = lane & 15;
  const int kq    = lane >> 4;

  const float* ctile = ctx + ((size_t)b * TLEN + (size_t)tc * 64) * UNITS;

  if (tid < 64) sS[tid] = 0.0f;

  f32x4 acc[4][8];
#pragma unroll
  for (int mt = 0; mt < 4; ++mt)
#pragma unroll
    for (int nt = 0; nt < 8; ++nt)
      acc[mt][nt] = (f32x4){0.0f, 0.0f, 0.0f, 0.0f};

  // ---- stage full tile: flat float4 loads (perfect coalescing) ----
  // iter j, thread t: floats f = 4*(j*256+t) -> row = 2j + (t>>7),
  // k = (t&127)*4.  Write 4 bf16 (8B) to As[row][k].
  {
    const float4* cbase = (const float4*)ctile;
    const int rbase = tid >> 7;            // 0 or 1
    const int kk    = (tid & 127) * 4;
#pragma unroll 8
    for (int j = 0; j < 32; ++j) {
      float4 v = cbase[j * 256 + tid];
      ushort4 q = make_ushort4(f2bf(v.x), f2bf(v.y), f2bf(v.z), f2bf(v.w));
      *(ushort4*)&As[2 * j + rbase][kk] = q;
    }
  }
  __syncthreads();                         // the ONLY barrier before epilogue

  // ---- barrier-free MFMA loop ----
  const bf16x8* bbase = (const bf16x8*)WaF + lane;
#pragma unroll
  for (int ks = 0; ks < 16; ++ks) {
    bf16x8 af[4];
#pragma unroll
    for (int mt = 0; mt < 4; ++mt)
      af[mt] = *(const bf16x8*)&As[mt * 16 + row_a][ks * 32 + kq * 8];
    bf16x8 bf[8];
#pragma unroll
    for (int nt = 0; nt < 8; ++nt)
      bf[nt] = bbase[(size_t)(ks * 32 + (w << 3) + nt) * 64];
    __builtin_amdgcn_s_setprio(1);
#pragma unroll
    for (int nt = 0; nt < 8; ++nt)
#pragma unroll
      for (int mt = 0; mt < 4; ++mt)
        acc[mt][nt] = __builtin_amdgcn_mfma_f32_16x16x32_bf16(af[mt], bf[nt], acc[mt][nt], 0, 0, 0);
    __builtin_amdgcn_s_setprio(0);
  }

  // ---- epilogue: s_t = sum_n tanh(y + u) * Va ----
  float uvals[8], vvals[8];
#pragma unroll
  for (int nt = 0; nt < 8; ++nt) {
    int n_g = (w << 7) + (nt << 4) + row_a;
    uvals[nt] = uvec[b * UNITS + n_g];
    vvals[nt] = Va[n_g];
  }
#pragma unroll
  for (int mt = 0; mt < 4; ++mt) {
#pragma unroll
    for (int r = 0; r < 4; ++r) {
      float v = 0.0f;
#pragma unroll
      for (int nt = 0; nt < 8; ++nt)
        v += fast_tanh(acc[mt][nt][r] + uvals[nt]) * vvals[nt];
      v += __shfl_xor(v, 1);
      v += __shfl_xor(v, 2);
      v += __shfl_xor(v, 4);
      v += __shfl_xor(v, 8);
      if (row_a == 0) atomicAdd(&sS[mt * 16 + kq * 4 + r], v);
    }
  }
  __syncthreads();
  if (tid < 64) sE[tid] = __expf(sS[tid]);
  __syncthreads();
  if (tid < 64) {
    float e = sE[tid];
#pragma unroll
    for (int off = 1; off < 64; off <<= 1) e += __shfl_xor(e, off);
    if (tid == 0) atomicAdd(&gL[b], e);
  }
  // ---- weighted context accumulation (tile L2-hot; coalesced re-read) ----
#pragma unroll
  for (int cc = 0; cc < 2; ++cc) {
    int c = cc * 256 + tid;
    float o = 0.0f;
#pragma unroll 8
    for (int t = 0; t < 64; ++t)
      o = fmaf(sE[t], ctile[t * UNITS + c], o);
    atomicAdd(&gO[b * UNITS + c], o);
  }
}

// ---------------------------------------------------------------------------
// cg = (gO/gL) @ attention_kernel.  grid = (24, 64).
// ---------------------------------------------------------------------------
__global__ void cg_kernel(const float* __restrict__ gO,
                          const float* __restrict__ gL,
                          const float* __restrict__ ak,
                          float* __restrict__ cg) {
  __shared__ float Asm[512];
  __shared__ float red[4][64];
  int m = blockIdx.y;
  float sc = __fdividef(1.0f, gL[m]);
  for (int k = threadIdx.x; k < 512; k += 256) Asm[k] = gO[m * 512 + k] * sc;
  __syncthreads();
  dot_core(Asm, red, ak, 1536, nullptr, nullptr, cg, 1536, 512, blockIdx.x, m);
}

// ---------------------------------------------------------------------------
// rec_h = (r * h_tm1) @ RK[:, 1024:], r-gate computed inline.  grid = (8,64).
// ---------------------------------------------------------------------------
__global__ void rech_kernel(const float* __restrict__ xg,
                            const float* __restrict__ reczr,
                            const float* __restrict__ cg,
                            const float* __restrict__ h,
                            const float* __restrict__ rkh,   // rk + 1024
                            float* __restrict__ out) {
  __shared__ float Asm[512];
  __shared__ float red[4][64];
  int m = blockIdx.y;
  for (int k = threadIdx.x; k < 512; k += 256) {
    float r = fast_sigmoid(xg[m * 1536 + 512 + k] + reczr[m * 1024 + 512 + k] +
                           cg[m * 1536 + 512 + k]);
    Asm[k] = r * h[m * 512 + k];
  }
  __syncthreads();
  dot_core(Asm, red, rkh, 1536, nullptr, nullptr, out, 512, 512, blockIdx.x, m);
}

// ---------------------------------------------------------------------------
// out = h_new @ Wo + bo, h_new computed inline; block x==0 stores h_new.
// grid = (8, 64).
// ---------------------------------------------------------------------------
__global__ void out_kernel(const float* __restrict__ xg,
                           const float* __restrict__ reczr,
                           const float* __restrict__ cg,
                           const float* __restrict__ rech,
                           const float* __restrict__ h_tm1,
                           const float* __restrict__ Wo,
                           const float* __restrict__ bo,
                           float* __restrict__ out,
                           float* __restrict__ hout) {
  __shared__ float Asm[512];
  __shared__ float red[4][64];
  int m = blockIdx.y;
  for (int k = threadIdx.x; k < 512; k += 256) {
    float z  = fast_sigmoid(xg[m * 1536 + k] + reczr[m * 1024 + k] + cg[m * 1536 + k]);
    float hb = fast_tanh(xg[m * 1536 + 1024 + k] + rech[m * 512 + k] +
                         cg[m * 1536 + 1024 + k]);
    float hn = z * h_tm1[m * 512 + k] + (1.0f - z) * hb;
    Asm[k] = hn;
    if (blockIdx.x == 0) hout[m * 512 + k] = hn;
  }
  __syncthreads();
  dot_core(Asm, red, Wo, 512, bo, nullptr, out, 512, 512, blockIdx.x, m);
}

// ---------------------------------------------------------------------------
extern "C" void kernel_launch(void* const* d_in, const int* in_sizes, int n_in,
                              void* d_out, int out_size, void* d_ws, size_t ws_size,
                              hipStream_t stream) {
  (void)in_sizes; (void)n_in; (void)out_size; (void)ws_size;
  const float* inputs = (const float*)d_in[0];
  const float* h_tm1  = (const float*)d_in[1];
  const float* ctx    = (const float*)d_in[2];
  const float* Wi     = (const float*)d_in[3];
  const float* bi     = (const float*)d_in[4];
  const float* kern   = (const float*)d_in[5];
  const float* rk     = (const float*)d_in[6];
  const float* ak     = (const float*)d_in[7];
  const float* bias   = (const float*)d_in[8];
  const float* Wa     = (const float*)d_in[9];
  const float* ba_w   = (const float*)d_in[10];
  const float* Ua     = (const float*)d_in[11];
  const float* ba_u   = (const float*)d_in[12];
  const float* Va     = (const float*)d_in[13];
  // d_in[14] = ba_v: unused (softmax is shift-invariant)
  const float* Wo     = (const float*)d_in[15];
  const float* bo     = (const float*)d_in[16];

  float* out = (float*)d_out;               // [64][512] out, then [64][512] h
  float* ws  = (float*)d_ws;
  unsigned short* WaF = (unsigned short*)ws;    // 262144 bf16
  float* gO     = ws + 131072;   // [64][512]
  float* gL     = ws + 163840;   // [64]
  float* xbuf   = ws + 163904;   // [64][512]
  float* xg     = ws + 196672;   // [64][1536]
  float* ubuf   = ws + 294976;   // [64][512]
  float* rec_zr = ws + 327744;   // [64][1024]
  float* cg     = ws + 393280;   // [64][1536]
  float* rech   = ws + 491584;   // [64][512]

  // L1: prep + x + u + rec_zr (all independent)
  stage1_kernel<<<3072, 256, 0, stream>>>(Wa, WaF, gO, gL,
                                          inputs, Wi, bi, xbuf,
                                          h_tm1, Ua, ba_u, ba_w, ubuf,
                                          rk, rec_zr);
  // L2: xg = x @ kernel + bias
  xg_kernel<<<dim3(24, 64), 256, 0, stream>>>(xbuf, kern, bias, xg);
  // L3: fused attention
  score_ctx_kernel<<<dim3(32, 64), 256, 0, stream>>>(ctx, WaF, ubuf, Va, gO, gL);
  // L4: cg = (gO/gL) @ attention_kernel
  cg_kernel<<<dim3(24, 64), 256, 0, stream>>>(gO, gL, ak, cg);
  // L5: rec_h = (r*h) @ RK[:, 1024:]  (r computed inline)
  rech_kernel<<<dim3(8, 64), 256, 0, stream>>>(xg, rec_zr, cg, h_tm1, rk + 1024, rech);
  // L6: h_new inline; out = h_new @ Wo + bo; h_new also stored
  out_kernel<<<dim3(8, 64), 256, 0, stream>>>(xg, rec_zr, cg, rech, h_tm1, Wo, bo,
                                              out, out + BATCH * UNITS);
}

// Round 5
// 520.590 us; speedup vs baseline: 1.0878x; 1.0255x over previous
//
#include <hip/hip_runtime.h>

#define UNITS 512
#define EMBD  256
#define BATCH 64
#define TLEN  2048

typedef __bf16 bf16x8 __attribute__((ext_vector_type(8)));
typedef float  f32x4  __attribute__((ext_vector_type(4)));

__device__ __forceinline__ unsigned short f2bf(float x) {
  return __builtin_bit_cast(unsigned short, (__bf16)x);
}
__device__ __forceinline__ float fast_tanh(float x) {
  float e = __expf(2.0f * x);
  return __fdividef(e - 1.0f, e + 1.0f);
}
__device__ __forceinline__ float fast_sigmoid(float x) {
  return __fdividef(1.0f, 1.0f + __expf(-x));
}

// ---------------------------------------------------------------------------
// Shared split-K small-GEMM core (after Asm staged in LDS):
//   out[m][bx*64 + cl] = dot(Asm[:K], Bm[:, c]) (+b1)(+b2)
// block = 256 = 64 cols x 4 k-segments.
// ---------------------------------------------------------------------------
__device__ __forceinline__ void dot_core(const float* Asm, float (*red)[64],
                                         const float* __restrict__ Bm, int ldb,
                                         const float* __restrict__ b1,
                                         const float* __restrict__ b2,
                                         float* __restrict__ out, int ldo,
                                         int K, int bx, int m) {
  const int cl = threadIdx.x & 63;
  const int ks = threadIdx.x >> 6;            // 0..3
  const int c  = (bx << 6) + cl;
  const int kl = K >> 2;
  const float* bp = Bm + (size_t)(ks * kl) * ldb + c;
  float acc = 0.0f;
#pragma unroll 8
  for (int kk = 0; kk < kl; ++kk)
    acc = fmaf(Asm[ks * kl + kk], bp[(size_t)kk * ldb], acc);
  red[ks][cl] = acc;
  __syncthreads();
  if (threadIdx.x < 64) {
    int cc = (bx << 6) + threadIdx.x;
    float v = red[0][threadIdx.x] + red[1][threadIdx.x] +
              red[2][threadIdx.x] + red[3][threadIdx.x];
    if (b1) v += b1[cc];
    if (b2) v += b2[cc];
    out[(size_t)m * ldo + cc] = v;
  }
}

// ---------------------------------------------------------------------------
// Launch 1 (fused, all independent): prep (Wa->frag-order bf16, zero gO/gL),
// x = inputs@Wi + bi, u = h@Ua + ba_u + ba_w, rec_zr = h@RK[:, :1024].
// prep: coalesced READS of Wa (scattered 2B writes to L2 don't stall).
// ---------------------------------------------------------------------------
__global__ void stage1_kernel(const float* __restrict__ Wa,
                              unsigned short* __restrict__ WaF,
                              float* __restrict__ gO, float* __restrict__ gL,
                              const float* __restrict__ inputs,
                              const float* __restrict__ Wi,
                              const float* __restrict__ bi,
                              float* __restrict__ xbuf,
                              const float* __restrict__ h_tm1,
                              const float* __restrict__ Ua,
                              const float* __restrict__ ba_u,
                              const float* __restrict__ ba_w,
                              float* __restrict__ ubuf,
                              const float* __restrict__ rk,
                              float* __restrict__ rec_zr) {
  __shared__ float Asm[512];
  __shared__ float red[4][64];
  int bid = blockIdx.x;
  if (bid < 1024) {                       // ---- prep ----
    int flat = bid * 256 + threadIdx.x;   // = k*512 + n  (coalesced read)
    int k = flat >> 9;
    int n = flat & 511;
    int ks = k >> 5;
    int hi = (k >> 3) & 3;
    int j  = k & 7;
    int l  = (hi << 4) | (n & 15);
    int nt = n >> 4;
    int idx = (ks << 14) | (nt << 9) | (l << 3) | j;
    WaF[idx] = f2bf(Wa[flat]);
    if (flat < BATCH * UNITS) gO[flat] = 0.0f;
    if (flat < BATCH)         gL[flat] = 0.0f;
    return;
  }
  bid -= 1024;
  if (bid < 512) {                        // ---- x = inputs@Wi + bi ----
    int bx = bid & 7, m = bid >> 3;
    for (int k = threadIdx.x; k < 256; k += 256) Asm[k] = inputs[m * 256 + k];
    __syncthreads();
    dot_core(Asm, red, Wi, 512, bi, nullptr, xbuf, 512, 256, bx, m);
    return;
  }
  bid -= 512;
  if (bid < 512) {                        // ---- u = h@Ua + ba_u + ba_w ----
    int bx = bid & 7, m = bid >> 3;
    for (int k = threadIdx.x; k < 512; k += 256) Asm[k] = h_tm1[m * 512 + k];
    __syncthreads();
    dot_core(Asm, red, Ua, 512, ba_u, ba_w, ubuf, 512, 512, bx, m);
    return;
  }
  bid -= 512;
  {                                       // ---- rec_zr = h@RK[:, :1024] ----
    int bx = bid & 15, m = bid >> 4;
    for (int k = threadIdx.x; k < 512; k += 256) Asm[k] = h_tm1[m * 512 + k];
    __syncthreads();
    dot_core(Asm, red, rk, 1536, nullptr, nullptr, rec_zr, 1024, 512, bx, m);
  }
}

// ---------------------------------------------------------------------------
// xg = x @ kernel + bias.  grid = (24, 64).
// ---------------------------------------------------------------------------
__global__ void xg_kernel(const float* __restrict__ xbuf,
                          const float* __restrict__ kern,
                          const float* __restrict__ bias,
                          float* __restrict__ xg) {
  __shared__ float Asm[512];
  __shared__ float red[4][64];
  int m = blockIdx.y;
  for (int k = threadIdx.x; k < 512; k += 256) Asm[k] = xbuf[m * 512 + k];
  __syncthreads();
  dot_core(Asm, red, kern, 1536, bias, nullptr, xg, 1536, 512, blockIdx.x, m);
}

// ---------------------------------------------------------------------------
// K3: fused attention-score + softmax partials + weighted context sum.
// v4 = v3 (full-tile LDS, one barrier, barrier-free MFMA loop) with the
// weighted-context epilogue reading the bf16 tile FROM LDS instead of
// re-reading ctx from global.  Theory: per-XCD resident A-tile footprint
// (64 blocks x 128 KB = 8 MB) exceeds the 4 MB L2, so the v3 re-read was
// served by L3 (~50-70k cy/round) — the dominant unmodeled cost.
// ---------------------------------------------------------------------------
__launch_bounds__(256, 2)
__global__ void score_ctx_kernel(const float* __restrict__ ctx,
                                 const unsigned short* __restrict__ WaF,
                                 const float* __restrict__ uvec,
                                 const float* __restrict__ Va,
                                 float* __restrict__ gO,
                                 float* __restrict__ gL) {
  __shared__ unsigned short As[64][520];     // 64 rows x 512 bf16 + 8 pad
  __shared__ float sS[64];
  __shared__ float sE[64];

  const int b   = blockIdx.y;
  const int tc  = blockIdx.x;
  const int tid = threadIdx.x;
  const int lane  = tid & 63;
  const int w     = tid >> 6;      // wave 0..3
  const int row_a = lane & 15;
  const int kq    = lane >> 4;

  const float* ctile = ctx + ((size_t)b * TLEN + (size_t)tc * 64) * UNITS;

  if (tid < 64) sS[tid] = 0.0f;

  // ---- stage full tile: flat float4 loads (perfect coalescing) ----
  // iter j, thread t: floats f = 4*(j*256+t) -> row = 2j + (t>>7),
  // k = (t&127)*4.  Write 4 bf16 (8B) to As[row][k].
  {
    const float4* cbase = (const float4*)ctile;
    const int rbase = tid >> 7;            // 0 or 1
    const int kk    = (tid & 127) * 4;
#pragma unroll 8
    for (int j = 0; j < 32; ++j) {
      float4 v = cbase[j * 256 + tid];
      ushort4 q = make_ushort4(f2bf(v.x), f2bf(v.y), f2bf(v.z), f2bf(v.w));
      *(ushort4*)&As[2 * j + rbase][kk] = q;
    }
  }
  __syncthreads();                         // the ONLY barrier before epilogue

  f32x4 acc[4][8];
#pragma unroll
  for (int mt = 0; mt < 4; ++mt)
#pragma unroll
    for (int nt = 0; nt < 8; ++nt)
      acc[mt][nt] = (f32x4){0.0f, 0.0f, 0.0f, 0.0f};

  // ---- barrier-free MFMA loop ----
  const bf16x8* bbase = (const bf16x8*)WaF + lane;
#pragma unroll
  for (int ks = 0; ks < 16; ++ks) {
    bf16x8 af[4];
#pragma unroll
    for (int mt = 0; mt < 4; ++mt)
      af[mt] = *(const bf16x8*)&As[mt * 16 + row_a][ks * 32 + kq * 8];
    bf16x8 bf[8];
#pragma unroll
    for (int nt = 0; nt < 8; ++nt)
      bf[nt] = bbase[(size_t)(ks * 32 + (w << 3) + nt) * 64];
    __builtin_amdgcn_s_setprio(1);
#pragma unroll
    for (int nt = 0; nt < 8; ++nt)
#pragma unroll
      for (int mt = 0; mt < 4; ++mt)
        acc[mt][nt] = __builtin_amdgcn_mfma_f32_16x16x32_bf16(af[mt], bf[nt], acc[mt][nt], 0, 0, 0);
    __builtin_amdgcn_s_setprio(0);
  }

  // ---- epilogue: s_t = sum_n tanh(y + u) * Va ----
  float uvals[8], vvals[8];
#pragma unroll
  for (int nt = 0; nt < 8; ++nt) {
    int n_g = (w << 7) + (nt << 4) + row_a;
    uvals[nt] = uvec[b * UNITS + n_g];
    vvals[nt] = Va[n_g];
  }
#pragma unroll
  for (int mt = 0; mt < 4; ++mt) {
#pragma unroll
    for (int r = 0; r < 4; ++r) {
      float v = 0.0f;
#pragma unroll
      for (int nt = 0; nt < 8; ++nt)
        v += fast_tanh(acc[mt][nt][r] + uvals[nt]) * vvals[nt];
      v += __shfl_xor(v, 1);
      v += __shfl_xor(v, 2);
      v += __shfl_xor(v, 4);
      v += __shfl_xor(v, 8);
      if (row_a == 0) atomicAdd(&sS[mt * 16 + kq * 4 + r], v);
    }
  }
  __syncthreads();
  if (tid < 64) sE[tid] = __expf(sS[tid]);
  __syncthreads();
  if (tid < 64) {
    float e = sE[tid];
#pragma unroll
    for (int off = 1; off < 64; off <<= 1) e += __shfl_xor(e, off);
    if (tid == 0) atomicAdd(&gL[b], e);
  }
  // ---- weighted context accumulation FROM LDS (bf16 tile) ----
  // thread handles columns c0 = 2*tid, 2*tid+1: one ds_read_b32 per row t
  // (consecutive-lane dwords -> 2-way bank aliasing = free).
  {
    const int c0 = tid * 2;
    float o0 = 0.0f, o1 = 0.0f;
#pragma unroll 16
    for (int t = 0; t < 64; ++t) {
      float e = sE[t];
      unsigned pr = *(const unsigned*)&As[t][c0];
      float a0 = __builtin_bit_cast(float, (pr & 0x0000ffffu) << 16);
      float a1 = __builtin_bit_cast(float, pr & 0xffff0000u);
      o0 = fmaf(e, a0, o0);
      o1 = fmaf(e, a1, o1);
    }
    atomicAdd(&gO[b * UNITS + c0],     o0);
    atomicAdd(&gO[b * UNITS + c0 + 1], o1);
  }
}

// ---------------------------------------------------------------------------
// cg = (gO/gL) @ attention_kernel.  grid = (24, 64).
// ---------------------------------------------------------------------------
__global__ void cg_kernel(const float* __restrict__ gO,
                          const float* __restrict__ gL,
                          const float* __restrict__ ak,
                          float* __restrict__ cg) {
  __shared__ float Asm[512];
  __shared__ float red[4][64];
  int m = blockIdx.y;
  float sc = __fdividef(1.0f, gL[m]);
  for (int k = threadIdx.x; k < 512; k += 256) Asm[k] = gO[m * 512 + k] * sc;
  __syncthreads();
  dot_core(Asm, red, ak, 1536, nullptr, nullptr, cg, 1536, 512, blockIdx.x, m);
}

// ---------------------------------------------------------------------------
// rec_h = (r * h_tm1) @ RK[:, 1024:], r-gate computed inline.  grid = (8,64).
// ---------------------------------------------------------------------------
__global__ void rech_kernel(const float* __restrict__ xg,
                            const float* __restrict__ reczr,
                            const float* __restrict__ cg,
                            const float* __restrict__ h,
                            const float* __restrict__ rkh,   // rk + 1024
                            float* __restrict__ out) {
  __shared__ float Asm[512];
  __shared__ float red[4][64];
  int m = blockIdx.y;
  for (int k = threadIdx.x; k < 512; k += 256) {
    float r = fast_sigmoid(xg[m * 1536 + 512 + k] + reczr[m * 1024 + 512 + k] +
                           cg[m * 1536 + 512 + k]);
    Asm[k] = r * h[m * 512 + k];
  }
  __syncthreads();
  dot_core(Asm, red, rkh, 1536, nullptr, nullptr, out, 512, 512, blockIdx.x, m);
}

// ---------------------------------------------------------------------------
// out = h_new @ Wo + bo, h_new computed inline; block x==0 stores h_new.
// grid = (8, 64).
// ---------------------------------------------------------------------------
__global__ void out_kernel(const float* __restrict__ xg,
                           const float* __restrict__ reczr,
                           const float* __restrict__ cg,
                           const float* __restrict__ rech,
                           const float* __restrict__ h_tm1,
                           const float* __restrict__ Wo,
                           const float* __restrict__ bo,
                           float* __restrict__ out,
                           float* __restrict__ hout) {
  __shared__ float Asm[512];
  __shared__ float red[4][64];
  int m = blockIdx.y;
  for (int k = threadIdx.x; k < 512; k += 256) {
    float z  = fast_sigmoid(xg[m * 1536 + k] + reczr[m * 1024 + k] + cg[m * 1536 + k]);
    float hb = fast_tanh(xg[m * 1536 + 1024 + k] + rech[m * 512 + k] +
                         cg[m * 1536 + 1024 + k]);
    float hn = z * h_tm1[m * 512 + k] + (1.0f - z) * hb;
    Asm[k] = hn;
    if (blockIdx.x == 0) hout[m * 512 + k] = hn;
  }
  __syncthreads();
  dot_core(Asm, red, Wo, 512, bo, nullptr, out, 512, 512, blockIdx.x, m);
}

// ---------------------------------------------------------------------------
extern "C" void kernel_launch(void* const* d_in, const int* in_sizes, int n_in,
                              void* d_out, int out_size, void* d_ws, size_t ws_size,
                              hipStream_t stream) {
  (void)in_sizes; (void)n_in; (void)out_size; (void)ws_size;
  const float* inputs = (const float*)d_in[0];
  const float* h_tm1  = (const float*)d_in[1];
  const float* ctx    = (const float*)d_in[2];
  const float* Wi     = (const float*)d_in[3];
  const float* bi     = (const float*)d_in[4];
  const float* kern   = (const float*)d_in[5];
  const float* rk     = (const float*)d_in[6];
  const float* ak     = (const float*)d_in[7];
  const float* bias   = (const float*)d_in[8];
  const float* Wa     = (const float*)d_in[9];
  const float* ba_w   = (const float*)d_in[10];
  const float* Ua     = (const float*)d_in[11];
  const float* ba_u   = (const float*)d_in[12];
  const float* Va     = (const float*)d_in[13];
  // d_in[14] = ba_v: unused (softmax is shift-invariant)
  const float* Wo     = (const float*)d_in[15];
  const float* bo     = (const float*)d_in[16];

  float* out = (float*)d_out;               // [64][512] out, then [64][512] h
  float* ws  = (float*)d_ws;
  unsigned short* WaF = (unsigned short*)ws;    // 262144 bf16
  float* gO     = ws + 131072;   // [64][512]
  float* gL     = ws + 163840;   // [64]
  float* xbuf   = ws + 163904;   // [64][512]
  float* xg     = ws + 196672;   // [64][1536]
  float* ubuf   = ws + 294976;   // [64][512]
  float* rec_zr = ws + 327744;   // [64][1024]
  float* cg     = ws + 393280;   // [64][1536]
  float* rech   = ws + 491584;   // [64][512]

  // L1: prep + x + u + rec_zr (all independent)
  stage1_kernel<<<3072, 256, 0, stream>>>(Wa, WaF, gO, gL,
                                          inputs, Wi, bi, xbuf,
                                          h_tm1, Ua, ba_u, ba_w, ubuf,
                                          rk, rec_zr);
  // L2: xg = x @ kernel + bias
  xg_kernel<<<dim3(24, 64), 256, 0, stream>>>(xbuf, kern, bias, xg);
  // L3: fused attention
  score_ctx_kernel<<<dim3(32, 64), 256, 0, stream>>>(ctx, WaF, ubuf, Va, gO, gL);
  // L4: cg = (gO/gL) @ attention_kernel
  cg_kernel<<<dim3(24, 64), 256, 0, stream>>>(gO, gL, ak, cg);
  // L5: rec_h = (r*h) @ RK[:, 1024:]  (r computed inline)
  rech_kernel<<<dim3(8, 64), 256, 0, stream>>>(xg, rec_zr, cg, h_tm1, rk + 1024, rech);
  // L6: h_new inline; out = h_new @ Wo + bo; h_new also stored
  out_kernel<<<dim3(8, 64), 256, 0, stream>>>(xg, rec_zr, cg, rech, h_tm1, Wo, bo,
                                              out, out + BATCH * UNITS);
}

// Round 8
// 519.959 us; speedup vs baseline: 1.0891x; 1.0012x over previous
//
#include <hip/hip_runtime.h>

#define UNITS 512
#define EMBD  256
#define BATCH 64
#define TLEN  2048

typedef __bf16 bf16x8 __attribute__((ext_vector_type(8)));
typedef float  f32x4  __attribute__((ext_vector_type(4)));

__device__ __forceinline__ unsigned short f2bf(float x) {
  return __builtin_bit_cast(unsigned short, (__bf16)x);
}
__device__ __forceinline__ float fast_tanh(float x) {
  float e = __expf(2.0f * x);
  return __fdividef(e - 1.0f, e + 1.0f);
}
__device__ __forceinline__ float fast_sigmoid(float x) {
  return __fdividef(1.0f, 1.0f + __expf(-x));
}

// ---------------------------------------------------------------------------
// Shared split-K small-GEMM core (after Asm staged in LDS):
//   out[m][bx*64 + cl] = dot(Asm[:K], Bm[:, c]) (+b1)(+b2)
// block = 256 = 64 cols x 4 k-segments.
// ---------------------------------------------------------------------------
__device__ __forceinline__ void dot_core(const float* Asm, float (*red)[64],
                                         const float* __restrict__ Bm, int ldb,
                                         const float* __restrict__ b1,
                                         const float* __restrict__ b2,
                                         float* __restrict__ out, int ldo,
                                         int K, int bx, int m) {
  const int cl = threadIdx.x & 63;
  const int ks = threadIdx.x >> 6;            // 0..3
  const int c  = (bx << 6) + cl;
  const int kl = K >> 2;
  const float* bp = Bm + (size_t)(ks * kl) * ldb + c;
  float acc = 0.0f;
#pragma unroll 8
  for (int kk = 0; kk < kl; ++kk)
    acc = fmaf(Asm[ks * kl + kk], bp[(size_t)kk * ldb], acc);
  red[ks][cl] = acc;
  __syncthreads();
  if (threadIdx.x < 64) {
    int cc = (bx << 6) + threadIdx.x;
    float v = red[0][threadIdx.x] + red[1][threadIdx.x] +
              red[2][threadIdx.x] + red[3][threadIdx.x];
    if (b1) v += b1[cc];
    if (b2) v += b2[cc];
    out[(size_t)m * ldo + cc] = v;
  }
}

// ---------------------------------------------------------------------------
// Launch 1 (fused, all independent): prep (Wa->frag-order bf16, zero gO/gL),
// x = inputs@Wi + bi, u = h@Ua + ba_u + ba_w, rec_zr = h@RK[:, :1024].
// prep: coalesced READS of Wa (scattered 2B writes to L2 don't stall).
// ---------------------------------------------------------------------------
__global__ void stage1_kernel(const float* __restrict__ Wa,
                              unsigned short* __restrict__ WaF,
                              float* __restrict__ gO, float* __restrict__ gL,
                              const float* __restrict__ inputs,
                              const float* __restrict__ Wi,
                              const float* __restrict__ bi,
                              float* __restrict__ xbuf,
                              const float* __restrict__ h_tm1,
                              const float* __restrict__ Ua,
                              const float* __restrict__ ba_u,
                              const float* __restrict__ ba_w,
                              float* __restrict__ ubuf,
                              const float* __restrict__ rk,
                              float* __restrict__ rec_zr) {
  __shared__ float Asm[512];
  __shared__ float red[4][64];
  int bid = blockIdx.x;
  if (bid < 1024) {                       // ---- prep ----
    int flat = bid * 256 + threadIdx.x;   // = k*512 + n  (coalesced read)
    int k = flat >> 9;
    int n = flat & 511;
    int ks = k >> 5;
    int hi = (k >> 3) & 3;
    int j  = k & 7;
    int l  = (hi << 4) | (n & 15);
    int nt = n >> 4;
    int idx = (ks << 14) | (nt << 9) | (l << 3) | j;
    WaF[idx] = f2bf(Wa[flat]);
    if (flat < BATCH * UNITS) gO[flat] = 0.0f;
    if (flat < BATCH)         gL[flat] = 0.0f;
    return;
  }
  bid -= 1024;
  if (bid < 512) {                        // ---- x = inputs@Wi + bi ----
    int bx = bid & 7, m = bid >> 3;
    for (int k = threadIdx.x; k < 256; k += 256) Asm[k] = inputs[m * 256 + k];
    __syncthreads();
    dot_core(Asm, red, Wi, 512, bi, nullptr, xbuf, 512, 256, bx, m);
    return;
  }
  bid -= 512;
  if (bid < 512) {                        // ---- u = h@Ua + ba_u + ba_w ----
    int bx = bid & 7, m = bid >> 3;
    for (int k = threadIdx.x; k < 512; k += 256) Asm[k] = h_tm1[m * 512 + k];
    __syncthreads();
    dot_core(Asm, red, Ua, 512, ba_u, ba_w, ubuf, 512, 512, bx, m);
    return;
  }
  bid -= 512;
  {                                       // ---- rec_zr = h@RK[:, :1024] ----
    int bx = bid & 15, m = bid >> 4;
    for (int k = threadIdx.x; k < 512; k += 256) Asm[k] = h_tm1[m * 512 + k];
    __syncthreads();
    dot_core(Asm, red, rk, 1536, nullptr, nullptr, rec_zr, 1024, 512, bx, m);
  }
}

// ---------------------------------------------------------------------------
// xg = x @ kernel + bias.  grid = (24, 64).
// ---------------------------------------------------------------------------
__global__ void xg_kernel(const float* __restrict__ xbuf,
                          const float* __restrict__ kern,
                          const float* __restrict__ bias,
                          float* __restrict__ xg) {
  __shared__ float Asm[512];
  __shared__ float red[4][64];
  int m = blockIdx.y;
  for (int k = threadIdx.x; k < 512; k += 256) Asm[k] = xbuf[m * 512 + k];
  __syncthreads();
  dot_core(Asm, red, kern, 1536, bias, nullptr, xg, 1536, 512, blockIdx.x, m);
}

// ---------------------------------------------------------------------------
// K3: fused attention-score + softmax partials + weighted context sum.
// v7 = v4 structure + batched staging WITHOUT sched_barrier/inline-asm
// (those correlate perfectly with harness container failures, r1/r2/r6/r7):
// a separate fully-unrolled 32-load loop into tmp[32], then a separate
// convert+ds_write loop.  The amdgcn scheduler hoists independent loads
// feeding a later loop, so most of the 32-deep issue window should
// survive without an explicit pin (Little's law: 8-deep caps the stage
// at ~1.2 TB/s; 32-deep x 8 waves/CU -> ~2.8-4 TB/s).
// ---------------------------------------------------------------------------
__launch_bounds__(256, 2)
__global__ void score_ctx_kernel(const float* __restrict__ ctx,
                                 const unsigned short* __restrict__ WaF,
                                 const float* __restrict__ uvec,
                                 const float* __restrict__ Va,
                                 float* __restrict__ gO,
                                 float* __restrict__ gL) {
  __shared__ unsigned short As[64][520];     // 64 rows x 512 bf16 + 8 pad
  __shared__ float sS[64];
  __shared__ float sE[64];

  const int b   = blockIdx.y;
  const int tc  = blockIdx.x;
  const int tid = threadIdx.x;
  const int lane  = tid & 63;
  const int w     = tid >> 6;      // wave 0..3
  const int row_a = lane & 15;
  const int kq    = lane >> 4;

  const float* ctile = ctx + ((size_t)b * TLEN + (size_t)tc * 64) * UNITS;

  if (tid < 64) sS[tid] = 0.0f;

  // ---- stage full tile: 32 batched float4 loads, then convert+write ----
  // iter j, thread t: floats f = 4*(j*256+t) -> row = 2j + (t>>7),
  // k = (t&127)*4.  Write 4 bf16 (8B) to As[row][k].
  {
    const float4* cbase = (const float4*)ctile;
    const int rbase = tid >> 7;            // 0 or 1
    const int kk    = (tid & 127) * 4;
    float4 tmp[32];
#pragma unroll
    for (int j = 0; j < 32; ++j)
      tmp[j] = cbase[j * 256 + tid];
#pragma unroll
    for (int j = 0; j < 32; ++j) {
      ushort4 q = make_ushort4(f2bf(tmp[j].x), f2bf(tmp[j].y), f2bf(tmp[j].z), f2bf(tmp[j].w));
      *(ushort4*)&As[2 * j + rbase][kk] = q;
    }
  }
  __syncthreads();                         // the ONLY barrier before epilogue

  f32x4 acc[4][8];
#pragma unroll
  for (int mt = 0; mt < 4; ++mt)
#pragma unroll
    for (int nt = 0; nt < 8; ++nt)
      acc[mt][nt] = (f32x4){0.0f, 0.0f, 0.0f, 0.0f};

  // ---- barrier-free MFMA loop ----
  const bf16x8* bbase = (const bf16x8*)WaF + lane;
#pragma unroll
  for (int ks = 0; ks < 16; ++ks) {
    bf16x8 af[4];
#pragma unroll
    for (int mt = 0; mt < 4; ++mt)
      af[mt] = *(const bf16x8*)&As[mt * 16 + row_a][ks * 32 + kq * 8];
    bf16x8 bf[8];
#pragma unroll
    for (int nt = 0; nt < 8; ++nt)
      bf[nt] = bbase[(size_t)(ks * 32 + (w << 3) + nt) * 64];
    __builtin_amdgcn_s_setprio(1);
#pragma unroll
    for (int nt = 0; nt < 8; ++nt)
#pragma unroll
      for (int mt = 0; mt < 4; ++mt)
        acc[mt][nt] = __builtin_amdgcn_mfma_f32_16x16x32_bf16(af[mt], bf[nt], acc[mt][nt], 0, 0, 0);
    __builtin_amdgcn_s_setprio(0);
  }

  // ---- epilogue: s_t = sum_n tanh(y + u) * Va ----
  float uvals[8], vvals[8];
#pragma unroll
  for (int nt = 0; nt < 8; ++nt) {
    int n_g = (w << 7) + (nt << 4) + row_a;
    uvals[nt] = uvec[b * UNITS + n_g];
    vvals[nt] = Va[n_g];
  }
#pragma unroll
  for (int mt = 0; mt < 4; ++mt) {
#pragma unroll
    for (int r = 0; r < 4; ++r) {
      float v = 0.0f;
#pragma unroll
      for (int nt = 0; nt < 8; ++nt)
        v += fast_tanh(acc[mt][nt][r] + uvals[nt]) * vvals[nt];
      v += __shfl_xor(v, 1);
      v += __shfl_xor(v, 2);
      v += __shfl_xor(v, 4);
      v += __shfl_xor(v, 8);
      if (row_a == 0) atomicAdd(&sS[mt * 16 + kq * 4 + r], v);
    }
  }
  __syncthreads();
  if (tid < 64) sE[tid] = __expf(sS[tid]);
  __syncthreads();
  if (tid < 64) {
    float e = sE[tid];
#pragma unroll
    for (int off = 1; off < 64; off <<= 1) e += __shfl_xor(e, off);
    if (tid == 0) atomicAdd(&gL[b], e);
  }
  // ---- weighted context accumulation FROM LDS (bf16 tile) ----
  // thread handles columns c0 = 2*tid, 2*tid+1: one ds_read_b32 per row t
  // (consecutive-lane dwords -> 2-way bank aliasing = free).
  {
    const int c0 = tid * 2;
    float o0 = 0.0f, o1 = 0.0f;
#pragma unroll 16
    for (int t = 0; t < 64; ++t) {
      float e = sE[t];
      unsigned pr = *(const unsigned*)&As[t][c0];
      float a0 = __builtin_bit_cast(float, (pr & 0x0000ffffu) << 16);
      float a1 = __builtin_bit_cast(float, pr & 0xffff0000u);
      o0 = fmaf(e, a0, o0);
      o1 = fmaf(e, a1, o1);
    }
    atomicAdd(&gO[b * UNITS + c0],     o0);
    atomicAdd(&gO[b * UNITS + c0 + 1], o1);
  }
}

// ---------------------------------------------------------------------------
// cg = (gO/gL) @ attention_kernel.  grid = (24, 64).
// ---------------------------------------------------------------------------
__global__ void cg_kernel(const float* __restrict__ gO,
                          const float* __restrict__ gL,
                          const float* __restrict__ ak,
                          float* __restrict__ cg) {
  __shared__ float Asm[512];
  __shared__ float red[4][64];
  int m = blockIdx.y;
  float sc = __fdividef(1.0f, gL[m]);
  for (int k = threadIdx.x; k < 512; k += 256) Asm[k] = gO[m * 512 + k] * sc;
  __syncthreads();
  dot_core(Asm, red, ak, 1536, nullptr, nullptr, cg, 1536, 512, blockIdx.x, m);
}

// ---------------------------------------------------------------------------
// rec_h = (r * h_tm1) @ RK[:, 1024:], r-gate computed inline.  grid = (8,64).
// ---------------------------------------------------------------------------
__global__ void rech_kernel(const float* __restrict__ xg,
                            const float* __restrict__ reczr,
                            const float* __restrict__ cg,
                            const float* __restrict__ h,
                            const float* __restrict__ rkh,   // rk + 1024
                            float* __restrict__ out) {
  __shared__ float Asm[512];
  __shared__ float red[4][64];
  int m = blockIdx.y;
  for (int k = threadIdx.x; k < 512; k += 256) {
    float r = fast_sigmoid(xg[m * 1536 + 512 + k] + reczr[m * 1024 + 512 + k] +
                           cg[m * 1536 + 512 + k]);
    Asm[k] = r * h[m * 512 + k];
  }
  __syncthreads();
  dot_core(Asm, red, rkh, 1536, nullptr, nullptr, out, 512, 512, blockIdx.x, m);
}

// ---------------------------------------------------------------------------
// out = h_new @ Wo + bo, h_new computed inline; block x==0 stores h_new.
// grid = (8, 64).
// ---------------------------------------------------------------------------
__global__ void out_kernel(const float* __restrict__ xg,
                           const float* __restrict__ reczr,
                           const float* __restrict__ cg,
                           const float* __restrict__ rech,
                           const float* __restrict__ h_tm1,
                           const float* __restrict__ Wo,
                           const float* __restrict__ bo,
                           float* __restrict__ out,
                           float* __restrict__ hout) {
  __shared__ float Asm[512];
  __shared__ float red[4][64];
  int m = blockIdx.y;
  for (int k = threadIdx.x; k < 512; k += 256) {
    float z  = fast_sigmoid(xg[m * 1536 + k] + reczr[m * 1024 + k] + cg[m * 1536 + k]);
    float hb = fast_tanh(xg[m * 1536 + 1024 + k] + rech[m * 512 + k] +
                         cg[m * 1536 + 1024 + k]);
    float hn = z * h_tm1[m * 512 + k] + (1.0f - z) * hb;
    Asm[k] = hn;
    if (blockIdx.x == 0) hout[m * 512 + k] = hn;
  }
  __syncthreads();
  dot_core(Asm, red, Wo, 512, bo, nullptr, out, 512, 512, blockIdx.x, m);
}

// ---------------------------------------------------------------------------
extern "C" void kernel_launch(void* const* d_in, const int* in_sizes, int n_in,
                              void* d_out, int out_size, void* d_ws, size_t ws_size,
                              hipStream_t stream) {
  (void)in_sizes; (void)n_in; (void)out_size; (void)ws_size;
  const float* inputs = (const float*)d_in[0];
  const float* h_tm1  = (const float*)d_in[1];
  const float* ctx    = (const float*)d_in[2];
  const float* Wi     = (const float*)d_in[3];
  const float* bi     = (const float*)d_in[4];
  const float* kern   = (const float*)d_in[5];
  const float* rk     = (const float*)d_in[6];
  const float* ak     = (const float*)d_in[7];
  const float* bias   = (const float*)d_in[8];
  const float* Wa     = (const float*)d_in[9];
  const float* ba_w   = (const float*)d_in[10];
  const float* Ua     = (const float*)d_in[11];
  const float* ba_u   = (const float*)d_in[12];
  const float* Va     = (const float*)d_in[13];
  // d_in[14] = ba_v: unused (softmax is shift-invariant)
  const float* Wo     = (const float*)d_in[15];
  const float* bo     = (const float*)d_in[16];

  float* out = (float*)d_out;               // [64][512] out, then [64][512] h
  float* ws  = (float*)d_ws;
  unsigned short* WaF = (unsigned short*)ws;    // 262144 bf16
  float* gO     = ws + 131072;   // [64][512]
  float* gL     = ws + 163840;   // [64]
  float* xbuf   = ws + 163904;   // [64][512]
  float* xg     = ws + 196672;   // [64][1536]
  float* ubuf   = ws + 294976;   // [64][512]
  float* rec_zr = ws + 327744;   // [64][1024]
  float* cg     = ws + 393280;   // [64][1536]
  float* rech   = ws + 491584;   // [64][512]

  // L1: prep + x + u + rec_zr (all independent)
  stage1_kernel<<<3072, 256, 0, stream>>>(Wa, WaF, gO, gL,
                                          inputs, Wi, bi, xbuf,
                                          h_tm1, Ua, ba_u, ba_w, ubuf,
                                          rk, rec_zr);
  // L2: xg = x @ kernel + bias
  xg_kernel<<<dim3(24, 64), 256, 0, stream>>>(xbuf, kern, bias, xg);
  // L3: fused attention
  score_ctx_kernel<<<dim3(32, 64), 256, 0, stream>>>(ctx, WaF, ubuf, Va, gO, gL);
  // L4: cg = (gO/gL) @ attention_kernel
  cg_kernel<<<dim3(24, 64), 256, 0, stream>>>(gO, gL, ak, cg);
  // L5: rec_h = (r*h) @ RK[:, 1024:]  (r computed inline)
  rech_kernel<<<dim3(8, 64), 256, 0, stream>>>(xg, rec_zr, cg, h_tm1, rk + 1024, rech);
  // L6: h_new inline; out = h_new @ Wo + bo; h_new also stored
  out_kernel<<<dim3(8, 64), 256, 0, stream>>>(xg, rec_zr, cg, rech, h_tm1, Wo, bo,
                                              out, out + BATCH * UNITS);
}